// Round 7
// baseline (129.144 us; speedup 1.0000x reference)
//
#include <hip/hip_runtime.h>
#include <hip/hip_fp16.h>
#include <math.h>

#define NEG_INF_F (-1e30f)
#define LRELU 0.2f

constexpr int Bb = 64, Ee = 512, IND = 1024, OUTD = 256;
constexpr int Mrows = Bb * Ee; // 32768

typedef __attribute__((ext_vector_type(8))) _Float16 half8;
typedef __attribute__((ext_vector_type(4))) _Float16 half4;
typedef __attribute__((ext_vector_type(4))) float floatx4;

// ---------------- Kernel 0: W fp32 -> fp16 ----------------
__global__ __launch_bounds__(256) void wconv_kernel(
    const float* __restrict__ W, _Float16* __restrict__ Whf)
{
    const int i = (blockIdx.x * 256 + threadIdx.x) * 4;
    const float4 w = *reinterpret_cast<const float4*>(&W[i]);
    half4 hh;
    hh[0] = (_Float16)w.x; hh[1] = (_Float16)w.y;
    hh[2] = (_Float16)w.z; hh[3] = (_Float16)w.w;
    *reinterpret_cast<half4*>(&Whf[i]) = hh;
}

// ---------------- Kernel 1: H = X @ W^T + b ----------------
// BM=64, BN=256(full), 256 thr = 4 waves, wave tile 64x64.
// NO LDS, NO barriers in the K-loop: A (fp32) and B (fp16) fragments are
// read directly from global into MFMA registers. A is shared by the 4
// waves via L1 (rally s_barrier every 4 steps keeps them aligned);
// B (512 KB Whf) is L2-resident. Manual depth-1 prefetch, named reg sets.
__global__ __launch_bounds__(256) void gemm_h_f16(
    const float* __restrict__ X, const _Float16* __restrict__ Whf,
    const float* __restrict__ Wb, const float* __restrict__ aw,
    const int* __restrict__ mask,
    _Float16* __restrict__ HmTh, float* __restrict__ s1, float* __restrict__ s2)
{
    __shared__ char lds_raw[35328];
    _Float16* Th   = (_Float16*)lds_raw;           // [256][64] 32 KB
    float*    s1p  = (float*)(lds_raw + 32768);    // [4][64]
    float*    s2p  = (float*)(lds_raw + 33792);    // [4][64]
    float*    mkfs = (float*)(lds_raw + 34816);    // [64]

    const int t  = threadIdx.x;
    const int w  = t >> 6, l = t & 63, ln = l & 15, lg = l >> 4;
    const int m0 = blockIdx.x * 64;

    // per-lane fragment base pointers
    const float* __restrict__ xr[4];
    const _Float16* __restrict__ br[4];
    #pragma unroll
    for (int mr = 0; mr < 4; ++mr)
        xr[mr] = X + (size_t)(m0 + mr * 16 + ln) * IND + lg * 8;
    #pragma unroll
    for (int nr = 0; nr < 4; ++nr)
        br[nr] = Whf + (size_t)(w * 64 + nr * 16 + ln) * IND + lg * 8;

    floatx4 acc[4][4];
    #pragma unroll
    for (int i = 0; i < 4; ++i)
        #pragma unroll
        for (int j = 0; j < 4; ++j)
            acc[i][j] = (floatx4)0.f;

    floatx4 A0[4][2], A1[4][2];
    half8   B0[4],    B1[4];

    auto load = [&](int ks, floatx4 (&Aq)[4][2], half8 (&Bq)[4]) {
        const int koff = ks * 32;
        #pragma unroll
        for (int mr = 0; mr < 4; ++mr) {
            Aq[mr][0] = *reinterpret_cast<const floatx4*>(xr[mr] + koff);
            Aq[mr][1] = *reinterpret_cast<const floatx4*>(xr[mr] + koff + 4);
        }
        #pragma unroll
        for (int nr = 0; nr < 4; ++nr)
            Bq[nr] = *reinterpret_cast<const half8*>(br[nr] + koff);
    };
    auto compute = [&](const floatx4 (&Aq)[4][2], const half8 (&Bq)[4]) {
        half8 af[4];
        #pragma unroll
        for (int mr = 0; mr < 4; ++mr) {
            half8 h;
            h[0] = (_Float16)Aq[mr][0][0]; h[1] = (_Float16)Aq[mr][0][1];
            h[2] = (_Float16)Aq[mr][0][2]; h[3] = (_Float16)Aq[mr][0][3];
            h[4] = (_Float16)Aq[mr][1][0]; h[5] = (_Float16)Aq[mr][1][1];
            h[6] = (_Float16)Aq[mr][1][2]; h[7] = (_Float16)Aq[mr][1][3];
            af[mr] = h;
        }
        __builtin_amdgcn_s_setprio(1);
        #pragma unroll
        for (int mr = 0; mr < 4; ++mr)
            #pragma unroll
            for (int nr = 0; nr < 4; ++nr)
                acc[mr][nr] = __builtin_amdgcn_mfma_f32_16x16x32_f16(
                    af[mr], Bq[nr], acc[mr][nr], 0, 0, 0);
        __builtin_amdgcn_s_setprio(0);
    };

    load(0, A0, B0);
    for (int p = 0; p < 16; ++p) {
        load(2 * p + 1, A1, B1);
        compute(A0, B0);
        if (p < 15) load(2 * p + 2, A0, B0);
        compute(A1, B1);
        if (p & 1) __builtin_amdgcn_s_barrier(); // rally: keep waves aligned for L1 A-reuse
    }

    // ---- epilogue ----
    if (t < 64) mkfs[t] = (float)mask[m0 + t];

    float bias[4], a1c[4], a2c[4];
    #pragma unroll
    for (int nr = 0; nr < 4; ++nr) {
        const int n = w * 64 + nr * 16 + ln;
        bias[nr] = Wb[n];
        a1c[nr]  = aw[n];
        a2c[nr]  = aw[OUTD + n];
    }
    float sv1[4][4], sv2[4][4];
    #pragma unroll
    for (int i = 0; i < 4; ++i)
        #pragma unroll
        for (int r = 0; r < 4; ++r) { sv1[i][r] = 0.f; sv2[i][r] = 0.f; }

    #pragma unroll
    for (int mr = 0; mr < 4; ++mr)
        #pragma unroll
        for (int nr = 0; nr < 4; ++nr) {
            const int o = w * 64 + nr * 16 + ln;
            half4 hh;
            #pragma unroll
            for (int rr = 0; rr < 4; ++rr) {
                const float hb = acc[mr][nr][rr] + bias[nr];
                sv1[mr][rr] += hb * a1c[nr];
                sv2[mr][rr] += hb * a2c[nr];
                hh[rr] = (_Float16)hb;
            }
            const int e = mr * 16 + lg * 4;
            *reinterpret_cast<half4*>(Th + o * 64 + (e ^ ((o & 7) << 3))) = hh;
        }

    #pragma unroll
    for (int mr = 0; mr < 4; ++mr)
        #pragma unroll
        for (int rr = 0; rr < 4; ++rr) {
            float v1 = sv1[mr][rr], v2 = sv2[mr][rr];
            #pragma unroll
            for (int off = 1; off < 16; off <<= 1) {
                v1 += __shfl_xor(v1, off, 64);
                v2 += __shfl_xor(v2, off, 64);
            }
            if (ln == 0) {
                const int e = mr * 16 + lg * 4 + rr;
                s1p[w * 64 + e] = v1;
                s2p[w * 64 + e] = v2;
            }
        }
    __syncthreads();

    if (t < 64) {
        s1[m0 + t] = s1p[t] + s1p[64 + t] + s1p[128 + t] + s1p[192 + t];
        s2[m0 + t] = s2p[t] + s2p[64 + t] + s2p[128 + t] + s2p[192 + t];
    }

    // coalesced masked HmT store: 128B contiguous per 16-lane group
    const int bIdx = m0 >> 9;
    const int e0   = m0 & 511;
    const int e4   = (t & 15) * 4;
    const float q0 = mkfs[e4 + 0], q1 = mkfs[e4 + 1];
    const float q2 = mkfs[e4 + 2], q3 = mkfs[e4 + 3];
    #pragma unroll
    for (int it = 0; it < 16; ++it) {
        const int o = it * 16 + (t >> 4);
        half4 vh = *reinterpret_cast<const half4*>(Th + o * 64 + (e4 ^ ((o & 7) << 3)));
        if (!(q0 > 0.f)) vh[0] = (_Float16)0.f;
        if (!(q1 > 0.f)) vh[1] = (_Float16)0.f;
        if (!(q2 > 0.f)) vh[2] = (_Float16)0.f;
        if (!(q3 > 0.f)) vh[3] = (_Float16)0.f;
        const size_t goff = ((size_t)(bIdx * OUTD + o) << 9) + e0 + e4;
        *reinterpret_cast<half4*>(&HmTh[goff]) = vh;
    }
}

// ---------------- Kernel 2: out[b] = softmax(scores[b]) @ (H[b]*m), MFMA ----
__global__ __launch_bounds__(256, 2) void attn_mfma(
    const _Float16* __restrict__ HmTh,
    const float* __restrict__ s1, const float* __restrict__ s2,
    const int* __restrict__ mask, const float* __restrict__ ab_ptr,
    float* __restrict__ Out)
{
    __shared__ float s2v[Ee];
    __shared__ float mkv[Ee];
    __shared__ float rowc[64];
    __shared__ float rmax[64];
    __shared__ int   rvv[64];
    __shared__ _Float16 Pl[2][64][32];
    __shared__ float Zp[64][4];
    __shared__ float zr[64];
    __shared__ float wmax[4];

    const int bid = blockIdx.x;
    const int b  = bid & 63;
    const int i0 = (bid >> 6) * 64;
    const int t  = threadIdx.x;
    const int w  = t >> 6, l = t & 63, ln = l & 15, lg = l >> 4;
    const float ab = ab_ptr[0];

    float lmax = -INFINITY;
    #pragma unroll
    for (int q = 0; q < 2; ++q) {
        const int j = t + q * 256;
        const float sv = s2[b * Ee + j];
        const float mv = (float)mask[b * Ee + j];
        s2v[j] = sv; mkv[j] = mv;
        if (mv > 0.f) lmax = fmaxf(lmax, sv);
    }
    #pragma unroll
    for (int off = 32; off; off >>= 1) lmax = fmaxf(lmax, __shfl_xor(lmax, off, 64));
    if (l == 0) wmax[w] = lmax;
    __syncthreads();
    const float s2max = fmaxf(fmaxf(wmax[0], wmax[1]), fmaxf(wmax[2], wmax[3]));
    const int anyvalid = (s2max > -1e37f) ? 1 : 0;
    if (t < 64) {
        const float c = s1[b * Ee + i0 + t] + ab;
        rowc[t] = c;
        const int mi = mask[b * Ee + i0 + t];
        rvv[t] = (mi != 0) & anyvalid;
        const float rm = c + s2max;
        rmax[t] = (rm >= 0.f) ? rm : LRELU * rm;
    }
    __syncthreads();

    const int pi = t >> 2;
    const int pj = (t & 3) * 8;
    const float prc = rowc[pi];
    const float prm = rmax[pi];
    const int   prv = rvv[pi];
    float zacc = 0.f;

    const size_t obase = (size_t)b * OUTD * Ee;
    const int o0 = w * 64;

    floatx4 acc[4][4];
    #pragma unroll
    for (int i = 0; i < 4; ++i)
        #pragma unroll
        for (int j = 0; j < 4; ++j)
            acc[i][j] = (floatx4)0.f;

    for (int ks = 0; ks < 16; ++ks) {
        const int k0  = ks * 32;
        const int buf = ks & 1;

        half8 ph;
        #pragma unroll
        for (int kk = 0; kk < 8; ++kk) {
            const int j = k0 + pj + kk;
            float pv;
            if (prv) {
                float sc = prc + s2v[j];
                sc = (sc >= 0.f) ? sc : LRELU * sc;
                pv = (mkv[j] > 0.f) ? __expf(sc - prm) : 0.f;
            } else {
                pv = 1.f;
            }
            const _Float16 hq = (_Float16)pv;
            ph[kk] = hq;
            zacc += (float)hq;
        }
        *reinterpret_cast<half8*>(&Pl[buf][pi][pj]) = ph;

        half8 bh[4];
        #pragma unroll
        for (int ot = 0; ot < 4; ++ot) {
            const size_t ro = obase + (size_t)(o0 + ot * 16 + ln) * Ee + k0 + lg * 8;
            bh[ot] = *reinterpret_cast<const half8*>(&HmTh[ro]);
        }
        __syncthreads();

        half8 af[4];
        #pragma unroll
        for (int mr = 0; mr < 4; ++mr)
            af[mr] = *reinterpret_cast<const half8*>(&Pl[buf][mr * 16 + ln][lg * 8]);
        #pragma unroll
        for (int mr = 0; mr < 4; ++mr)
            #pragma unroll
            for (int ot = 0; ot < 4; ++ot)
                acc[mr][ot] = __builtin_amdgcn_mfma_f32_16x16x32_f16(
                    af[mr], bh[ot], acc[mr][ot], 0, 0, 0);
    }

    Zp[pi][t & 3] = zacc;
    __syncthreads();
    if (t < 64) {
        const float z = Zp[t][0] + Zp[t][1] + Zp[t][2] + Zp[t][3];
        zr[t] = 1.f / z;
    }
    __syncthreads();

    float* __restrict__ Ob = Out + ((size_t)b * Ee + i0) * OUTD;
    #pragma unroll
    for (int mr = 0; mr < 4; ++mr)
        #pragma unroll
        for (int rr = 0; rr < 4; ++rr) {
            const int i = mr * 16 + lg * 4 + rr;
            const float rzi = zr[i];
            #pragma unroll
            for (int ot = 0; ot < 4; ++ot)
                Ob[(size_t)i * OUTD + o0 + ot * 16 + ln] = acc[mr][ot][rr] * rzi;
        }
}

extern "C" void kernel_launch(void* const* d_in, const int* in_sizes, int n_in,
                              void* d_out, int out_size, void* d_ws, size_t ws_size,
                              hipStream_t stream) {
    const float* X    = (const float*)d_in[0];
    // d_in[1] = adj : unused by the reference (dead input)
    const int*   mask = (const int*)d_in[2];
    const float* Ww   = (const float*)d_in[3];
    const float* Wb   = (const float*)d_in[4];
    const float* aw   = (const float*)d_in[5];
    const float* ab   = (const float*)d_in[6];
    float* out = (float*)d_out;

    _Float16* HmTh = (_Float16*)d_ws;                     // [64][256][512] fp16 = 16 MB
    float* s1 = (float*)(HmTh + (size_t)Bb * OUTD * Ee);  // 128 KB
    float* s2 = s1 + Mrows;                               // 128 KB
    _Float16* Whf = (_Float16*)(s2 + Mrows);              // 512 KB

    wconv_kernel<<<OUTD * IND / (256 * 4), 256, 0, stream>>>(Ww, Whf);
    gemm_h_f16<<<Mrows / 64, 256, 0, stream>>>(X, Whf, Wb, aw, mask, HmTh, s1, s2);
    attn_mfma<<<Bb * (Ee / 64), 256, 0, stream>>>(HmTh, s1, s2, mask, ab, out);
}

// Round 8
// 69.447 us; speedup vs baseline: 1.8596x; 1.8596x over previous
//
#include <hip/hip_runtime.h>
#include <hip/hip_fp16.h>
#include <math.h>

#define NEG_INF_F (-1e30f)
#define LRELU 0.2f

constexpr int Bb = 64, Ee = 512, IND = 1024, OUTD = 256;
constexpr int Mrows = Bb * Ee; // 32768

typedef __attribute__((ext_vector_type(8))) _Float16 half8;
typedef __attribute__((ext_vector_type(4))) _Float16 half4;
typedef __attribute__((ext_vector_type(4))) float floatx4;

#define AS1 __attribute__((address_space(1)))
#define AS3 __attribute__((address_space(3)))

// ---------------- Kernel 0: W fp32 -> fp16 ----------------
__global__ __launch_bounds__(256) void wconv_kernel(
    const float* __restrict__ W, _Float16* __restrict__ Whf)
{
    const int i = (blockIdx.x * 256 + threadIdx.x) * 4;
    const float4 w = *reinterpret_cast<const float4*>(&W[i]);
    half4 hh;
    hh[0] = (_Float16)w.x; hh[1] = (_Float16)w.y;
    hh[2] = (_Float16)w.z; hh[3] = (_Float16)w.w;
    *reinterpret_cast<half4*>(&Whf[i]) = hh;
}

// ---------------- Kernel 1: H = X @ W^T + b ----------------
// BM=128, BN=256(full), BK=32, 512 thr = 8 waves (2x4), wave tile 64x64.
// ALL staging via global_load_lds (A raw fp32, converted at frag build; B fp16).
// Triple-buffered, counted vmcnt(4), one barrier per step. 256 blocks = 1/CU.
// Halves B fabric traffic vs BM=64 (each block still reads all of Whf once).
__global__ __launch_bounds__(512, 2) void gemm_h_f16(
    const float* __restrict__ X, const _Float16* __restrict__ Whf,
    const float* __restrict__ Wb, const float* __restrict__ aw,
    const int* __restrict__ mask,
    _Float16* __restrict__ HmTh, float* __restrict__ s1, float* __restrict__ s2)
{
    __shared__ char lds_raw[98304];
    float*    Af  = (float*)lds_raw;               // [3][128][32] fp32, 48 KB
    _Float16* Bf  = (_Float16*)(lds_raw + 49152);  // [3][256][32] fp16, 48 KB
    // epilogue overlays:
    _Float16* Th   = (_Float16*)lds_raw;           // [256][128] 64 KB
    float*    s1p  = (float*)(lds_raw + 65536);    // [4][128]
    float*    s2p  = (float*)(lds_raw + 67584);    // [4][128]
    float*    mkfs = (float*)(lds_raw + 69632);    // [128]

    const int t  = threadIdx.x;
    const int w  = t >> 6, l = t & 63, ln = l & 15, lg = l >> 4;
    const int wr = w >> 2, wc = w & 3;
    const int m0 = blockIdx.x * 128;

    // A stage: 2 instrs/wave, instr i covers rows w*16 + i*8 .. +8 (1 KB each).
    const int arl = l >> 3;                   // row within 8-row group
    const int agl = (l & 7) ^ arl;            // pre-swizzled source granule (4 fp32)
    // B stage: 2 instrs/wave, instr i covers rows w*32 + i*16 .. +16 (1 KB each).
    const int brl = l >> 2;                   // row within 16-row group
    const int bgl = (l & 3) ^ ((l >> 3) & 3); // pre-swizzled source granule (8 halves)

    floatx4 acc[4][4];
    #pragma unroll
    for (int i = 0; i < 4; ++i)
        #pragma unroll
        for (int j = 0; j < 4; ++j)
            acc[i][j] = (floatx4)0.f;

    auto stageA = [&](int kc, int aoff) {
        #pragma unroll
        for (int i = 0; i < 2; ++i) {
            const int rbase = w * 16 + i * 8;
            const size_t src = (size_t)(m0 + rbase + arl) * IND + kc * 32 + agl * 4;
            __builtin_amdgcn_global_load_lds(
                (const AS1 unsigned int*)(X + src),
                (AS3 unsigned int*)(Af + aoff + rbase * 32), 16, 0, 0);
        }
    };
    auto stageB = [&](int kc, int boff) {
        #pragma unroll
        for (int i = 0; i < 2; ++i) {
            const int nbase = w * 32 + i * 16;
            const size_t src = (size_t)(nbase + brl) * IND + kc * 32 + bgl * 8;
            __builtin_amdgcn_global_load_lds(
                (const AS1 unsigned int*)(Whf + src),
                (AS3 unsigned int*)(Bf + boff + nbase * 32), 16, 0, 0);
        }
    };

    // buffer offsets (elements), rotate {cur, next, stagetgt}
    int aO0 = 0, aO1 = 4096, aO2 = 8192;
    int bO0 = 0, bO1 = 8192, bO2 = 16384;

    // ---- prologue ----
    stageA(0, aO0); stageB(0, bO0);
    stageA(1, aO1); stageB(1, bO1);
    asm volatile("s_waitcnt vmcnt(4) lgkmcnt(0)" ::: "memory"); // k0 complete
    __builtin_amdgcn_sched_barrier(0);
    __builtin_amdgcn_s_barrier();
    __builtin_amdgcn_sched_barrier(0);

    for (int ts = 0; ts < 32; ++ts) {
        if (ts < 30) { stageA(ts + 2, aO2); stageB(ts + 2, bO2); }
        __builtin_amdgcn_sched_barrier(0);

        // ---- fragments from slot0 ----
        half8 bfrag[4];
        #pragma unroll
        for (int nr = 0; nr < 4; ++nr) {
            const int n = wc * 64 + nr * 16 + ln;
            const int phys = lg ^ ((n >> 1) & 3);
            bfrag[nr] = *reinterpret_cast<const half8*>(Bf + bO0 + n * 32 + phys * 8);
        }
        half8 afrag[4];
        #pragma unroll
        for (int mr = 0; mr < 4; ++mr) {
            const int r = wr * 64 + mr * 16 + ln;
            const int g0 = (lg * 2) ^ (r & 7);
            const int g1 = (lg * 2 + 1) ^ (r & 7);
            const floatx4 a0 = *reinterpret_cast<const floatx4*>(Af + aO0 + r * 32 + g0 * 4);
            const floatx4 a1 = *reinterpret_cast<const floatx4*>(Af + aO0 + r * 32 + g1 * 4);
            half8 h;
            h[0] = (_Float16)a0[0]; h[1] = (_Float16)a0[1];
            h[2] = (_Float16)a0[2]; h[3] = (_Float16)a0[3];
            h[4] = (_Float16)a1[0]; h[5] = (_Float16)a1[1];
            h[6] = (_Float16)a1[2]; h[7] = (_Float16)a1[3];
            afrag[mr] = h;
        }

        __builtin_amdgcn_s_setprio(1);
        #pragma unroll
        for (int mr = 0; mr < 4; ++mr)
            #pragma unroll
            for (int nr = 0; nr < 4; ++nr)
                acc[mr][nr] = __builtin_amdgcn_mfma_f32_16x16x32_f16(
                    afrag[mr], bfrag[nr], acc[mr][nr], 0, 0, 0);
        __builtin_amdgcn_s_setprio(0);

        if (ts < 30) asm volatile("s_waitcnt vmcnt(4) lgkmcnt(0)" ::: "memory");
        else         asm volatile("s_waitcnt vmcnt(0) lgkmcnt(0)" ::: "memory");
        __builtin_amdgcn_sched_barrier(0);
        __builtin_amdgcn_s_barrier();
        __builtin_amdgcn_sched_barrier(0);

        int tmp = aO0; aO0 = aO1; aO1 = aO2; aO2 = tmp;
        tmp = bO0; bO0 = bO1; bO1 = bO2; bO2 = tmp;
    }

    // ---- epilogue ----
    if (t < 128) mkfs[t] = (float)mask[m0 + t];

    float bias[4], a1c[4], a2c[4];
    #pragma unroll
    for (int nr = 0; nr < 4; ++nr) {
        const int n = wc * 64 + nr * 16 + ln;
        bias[nr] = Wb[n];
        a1c[nr]  = aw[n];
        a2c[nr]  = aw[OUTD + n];
    }
    float sv1[4][4], sv2[4][4];
    #pragma unroll
    for (int i = 0; i < 4; ++i)
        #pragma unroll
        for (int r = 0; r < 4; ++r) { sv1[i][r] = 0.f; sv2[i][r] = 0.f; }

    #pragma unroll
    for (int mr = 0; mr < 4; ++mr)
        #pragma unroll
        for (int nr = 0; nr < 4; ++nr) {
            const int o = wc * 64 + nr * 16 + ln;
            half4 hh;
            #pragma unroll
            for (int rr = 0; rr < 4; ++rr) {
                const float hb = acc[mr][nr][rr] + bias[nr];
                sv1[mr][rr] += hb * a1c[nr];
                sv2[mr][rr] += hb * a2c[nr];
                hh[rr] = (_Float16)hb;
            }
            const int e = wr * 64 + mr * 16 + lg * 4;
            *reinterpret_cast<half4*>(Th + o * 128 + (e ^ ((o & 7) << 3))) = hh;
        }

    #pragma unroll
    for (int mr = 0; mr < 4; ++mr)
        #pragma unroll
        for (int rr = 0; rr < 4; ++rr) {
            float v1 = sv1[mr][rr], v2 = sv2[mr][rr];
            #pragma unroll
            for (int off = 1; off < 16; off <<= 1) {
                v1 += __shfl_xor(v1, off, 64);
                v2 += __shfl_xor(v2, off, 64);
            }
            if (ln == 0) {
                const int e = wr * 64 + mr * 16 + lg * 4 + rr;
                s1p[wc * 128 + e] = v1;
                s2p[wc * 128 + e] = v2;
            }
        }
    __syncthreads();

    if (t < 128) {
        s1[m0 + t] = s1p[t] + s1p[128 + t] + s1p[256 + t] + s1p[384 + t];
        s2[m0 + t] = s2p[t] + s2p[128 + t] + s2p[256 + t] + s2p[384 + t];
    }

    // coalesced masked HmT store: 256B contiguous per o-row
    const int bIdx = m0 >> 9;
    const int e0   = m0 & 511;
    const int e4   = (t & 31) * 4;
    const float q0 = mkfs[e4 + 0], q1 = mkfs[e4 + 1];
    const float q2 = mkfs[e4 + 2], q3 = mkfs[e4 + 3];
    #pragma unroll
    for (int it = 0; it < 16; ++it) {
        const int o = it * 16 + (t >> 5);
        half4 vh = *reinterpret_cast<const half4*>(Th + o * 128 + (e4 ^ ((o & 7) << 3)));
        if (!(q0 > 0.f)) vh[0] = (_Float16)0.f;
        if (!(q1 > 0.f)) vh[1] = (_Float16)0.f;
        if (!(q2 > 0.f)) vh[2] = (_Float16)0.f;
        if (!(q3 > 0.f)) vh[3] = (_Float16)0.f;
        const size_t goff = ((size_t)(bIdx * OUTD + o) << 9) + e0 + e4;
        *reinterpret_cast<half4*>(&HmTh[goff]) = vh;
    }
}

// ---------------- Kernel 2: out[b] = softmax(scores[b]) @ (H[b]*m), MFMA ----
__global__ __launch_bounds__(256, 2) void attn_mfma(
    const _Float16* __restrict__ HmTh,
    const float* __restrict__ s1, const float* __restrict__ s2,
    const int* __restrict__ mask, const float* __restrict__ ab_ptr,
    float* __restrict__ Out)
{
    __shared__ float s2v[Ee];
    __shared__ float mkv[Ee];
    __shared__ float rowc[64];
    __shared__ float rmax[64];
    __shared__ int   rvv[64];
    __shared__ _Float16 Pl[2][64][32];
    __shared__ float Zp[64][4];
    __shared__ float zr[64];
    __shared__ float wmax[4];

    const int bid = blockIdx.x;
    const int b  = bid & 63;
    const int i0 = (bid >> 6) * 64;
    const int t  = threadIdx.x;
    const int w  = t >> 6, l = t & 63, ln = l & 15, lg = l >> 4;
    const float ab = ab_ptr[0];

    float lmax = -INFINITY;
    #pragma unroll
    for (int q = 0; q < 2; ++q) {
        const int j = t + q * 256;
        const float sv = s2[b * Ee + j];
        const float mv = (float)mask[b * Ee + j];
        s2v[j] = sv; mkv[j] = mv;
        if (mv > 0.f) lmax = fmaxf(lmax, sv);
    }
    #pragma unroll
    for (int off = 32; off; off >>= 1) lmax = fmaxf(lmax, __shfl_xor(lmax, off, 64));
    if (l == 0) wmax[w] = lmax;
    __syncthreads();
    const float s2max = fmaxf(fmaxf(wmax[0], wmax[1]), fmaxf(wmax[2], wmax[3]));
    const int anyvalid = (s2max > -1e37f) ? 1 : 0;
    if (t < 64) {
        const float c = s1[b * Ee + i0 + t] + ab;
        rowc[t] = c;
        const int mi = mask[b * Ee + i0 + t];
        rvv[t] = (mi != 0) & anyvalid;
        const float rm = c + s2max;
        rmax[t] = (rm >= 0.f) ? rm : LRELU * rm;
    }
    __syncthreads();

    const int pi = t >> 2;
    const int pj = (t & 3) * 8;
    const float prc = rowc[pi];
    const float prm = rmax[pi];
    const int   prv = rvv[pi];
    float zacc = 0.f;

    const size_t obase = (size_t)b * OUTD * Ee;
    const int o0 = w * 64;

    floatx4 acc[4][4];
    #pragma unroll
    for (int i = 0; i < 4; ++i)
        #pragma unroll
        for (int j = 0; j < 4; ++j)
            acc[i][j] = (floatx4)0.f;

    for (int ks = 0; ks < 16; ++ks) {
        const int k0  = ks * 32;
        const int buf = ks & 1;

        half8 ph;
        #pragma unroll
        for (int kk = 0; kk < 8; ++kk) {
            const int j = k0 + pj + kk;
            float pv;
            if (prv) {
                float sc = prc + s2v[j];
                sc = (sc >= 0.f) ? sc : LRELU * sc;
                pv = (mkv[j] > 0.f) ? __expf(sc - prm) : 0.f;
            } else {
                pv = 1.f;
            }
            const _Float16 hq = (_Float16)pv;
            ph[kk] = hq;
            zacc += (float)hq;
        }
        *reinterpret_cast<half8*>(&Pl[buf][pi][pj]) = ph;

        half8 bh[4];
        #pragma unroll
        for (int ot = 0; ot < 4; ++ot) {
            const size_t ro = obase + (size_t)(o0 + ot * 16 + ln) * Ee + k0 + lg * 8;
            bh[ot] = *reinterpret_cast<const half8*>(&HmTh[ro]);
        }
        __syncthreads();

        half8 af[4];
        #pragma unroll
        for (int mr = 0; mr < 4; ++mr)
            af[mr] = *reinterpret_cast<const half8*>(&Pl[buf][mr * 16 + ln][lg * 8]);
        #pragma unroll
        for (int mr = 0; mr < 4; ++mr)
            #pragma unroll
            for (int ot = 0; ot < 4; ++ot)
                acc[mr][ot] = __builtin_amdgcn_mfma_f32_16x16x32_f16(
                    af[mr], bh[ot], acc[mr][ot], 0, 0, 0);
    }

    Zp[pi][t & 3] = zacc;
    __syncthreads();
    if (t < 64) {
        const float z = Zp[t][0] + Zp[t][1] + Zp[t][2] + Zp[t][3];
        zr[t] = 1.f / z;
    }
    __syncthreads();

    float* __restrict__ Ob = Out + ((size_t)b * Ee + i0) * OUTD;
    #pragma unroll
    for (int mr = 0; mr < 4; ++mr)
        #pragma unroll
        for (int rr = 0; rr < 4; ++rr) {
            const int i = mr * 16 + lg * 4 + rr;
            const float rzi = zr[i];
            #pragma unroll
            for (int ot = 0; ot < 4; ++ot)
                Ob[(size_t)i * OUTD + o0 + ot * 16 + ln] = acc[mr][ot][rr] * rzi;
        }
}

extern "C" void kernel_launch(void* const* d_in, const int* in_sizes, int n_in,
                              void* d_out, int out_size, void* d_ws, size_t ws_size,
                              hipStream_t stream) {
    const float* X    = (const float*)d_in[0];
    // d_in[1] = adj : unused by the reference (dead input)
    const int*   mask = (const int*)d_in[2];
    const float* Ww   = (const float*)d_in[3];
    const float* Wb   = (const float*)d_in[4];
    const float* aw   = (const float*)d_in[5];
    const float* ab   = (const float*)d_in[6];
    float* out = (float*)d_out;

    _Float16* HmTh = (_Float16*)d_ws;                     // [64][256][512] fp16 = 16 MB
    float* s1 = (float*)(HmTh + (size_t)Bb * OUTD * Ee);  // 128 KB
    float* s2 = s1 + Mrows;                               // 128 KB
    _Float16* Whf = (_Float16*)(s2 + Mrows);              // 512 KB

    wconv_kernel<<<OUTD * IND / (256 * 4), 256, 0, stream>>>(Ww, Whf);
    gemm_h_f16<<<Mrows / 128, 512, 0, stream>>>(X, Whf, Wb, aw, mask, HmTh, s1, s2);
    attn_mfma<<<Bb * (Ee / 64), 256, 0, stream>>>(HmTh, s1, s2, mask, ab, out);
}